// Round 19
// baseline (56.306 us; speedup 1.0000x reference)
//
#include <hip/hip_runtime.h>

// SSKernelNPLR, 2-kernel pipeline. H=256, N=32 (M=64 conj-extended), R=1, L=8192.
// K1 ssk_S (grid 512, 512 thr, lb(512,2) -> cap 128): contour, quad node
//    groups, register-resident params, deferred a,b, DPP quad reduce,
//    U1/U2 real-part deferral. Node loop unrolled x2 for ILP (loop1 of node
//    i+1 overlaps reduce/q chain of node i). Sws [h][half][2m+bit].
// K2 ssk_B (grid 256, 1024 thr, lb(1024,2) -> cap 128): combine (2 halves) +
//    C~ + poly-Cauchy with deferred A/B accumulation; Woodbury + (1+iT);
//    real-irfft packing; 6-stage radix-4 Stockham inverse FFT -> out.
//    (r18-verified, unchanged)

#define HH 256
#define NN 32
#define MF 4096

typedef float2 c32;

__device__ __forceinline__ c32 cmul(c32 a, c32 b){ return make_float2(a.x*b.x - a.y*b.y, a.x*b.y + a.y*b.x); }
__device__ __forceinline__ c32 cadd(c32 a, c32 b){ return make_float2(a.x+b.x, a.y+b.y); }
__device__ __forceinline__ c32 csub(c32 a, c32 b){ return make_float2(a.x-b.x, a.y-b.y); }
__device__ __forceinline__ c32 cconjf(c32 a){ return make_float2(a.x, -a.y); }
__device__ __forceinline__ float frcp(float x){ return __builtin_amdgcn_rcpf(x); }

// DPP quad_perm lane swaps (VALU pipe): xor1 = [1,0,3,2], xor2 = [2,3,0,1]
__device__ __forceinline__ float dpp_xor1(float x){
  return __int_as_float(__builtin_amdgcn_update_dpp(0, __float_as_int(x), 0xB1, 0xF, 0xF, true));
}
__device__ __forceinline__ float dpp_xor2(float x){
  return __int_as_float(__builtin_amdgcn_update_dpp(0, __float_as_int(x), 0x4E, 0xF, 0xF, true));
}

// ---------------- K1: contour (r16 structure + unroll-2 node loop) ---------
__global__ __launch_bounds__(512, 2)
void ssk_S(const float* __restrict__ log_dt, const float* __restrict__ invwr,
           const float* __restrict__ wim, const float* __restrict__ Pin,
           const float* __restrict__ Cin, float* __restrict__ Sws)
{
  __shared__ __align__(16) float4 tA[36];   // (d.x, d.y, alpha_a, beta_a), pad m+(m>>3)
  __shared__ c32 tB[36];                    // (alpha_b, beta_b)
  __shared__ float red[8*64];               // [wave][component]
  const int bid = blockIdx.x;
  const int h = bid >> 1;
  const int base = (bid & 1) << 11;         // 0 or 2048
  const int tid = threadIdx.x;

  if (tid < 64) {
    const int n = tid & 31;
    const bool cj = tid >= 32;
    const float dt = expf(log_dt[h]);
    float wr = -expf(invwr[h*NN + n]);
    float wi = wim[h*NN + n];
    if (cj) wi = -wi;
    const float tdt = 2.0f / dt;
    float dr = tdt - wr, di = -wi;
    float invd = 1.0f / (dr*dr + di*di);
    c32 D = make_float2(dr*invd, -di*invd);   // 1/(2/dt - w)
    c32 E = make_float2(tdt + wr, wi);        // 2/dt + w
    c32 Pf = make_float2(Pin[(h*NN+n)*2], Pin[(h*NN+n)*2+1]);
    if (cj) Pf.y = -Pf.y;
    c32 Cf = make_float2(Cin[(h*NN+n)*2], Cin[(h*NN+n)*2+1]);
    if (cj) Cf.y = -Cf.y;
    float rm = (Pf.x*Pf.x + Pf.y*Pf.y) * D.x;
    #pragma unroll
    for (int off = 32; off >= 1; off >>= 1) rm += __shfl_xor(rm, off, 64);
    rm += 1.0f;
    c32 Rc = cmul(cconjf(Pf), D);
    float invrm = 1.0f / rm;
    Rc.x *= invrm; Rc.y *= invrm;
    c32 RP = cmul(Rc, Pf);
    #pragma unroll
    for (int off = 32; off >= 1; off >>= 1) {
      RP.x += __shfl_xor(RP.x, off, 64);
      RP.y += __shfl_xor(RP.y, off, 64);
    }
    c32 Q2 = cconjf(Pf);
    c32 s  = csub(cmul(Rc, E), cmul(RP, Q2));
    c32 u  = cadd(Q2, s);                     // dA = diag(dd) - pp u^T
    c32 dd = cmul(D, E);
    c32 pp = cmul(D, Pf);
    c32 pc = cmul(pp, Cf);
    c32 pu = cmul(pp, u);
    if (tid < 32) {
      const int pm = tid + (tid >> 3);
      float ba = 2.0f*(pc.x*dd.x + pc.y*dd.y);
      float bb = 2.0f*(pu.x*dd.x + pu.y*dd.y);
      tA[pm] = make_float4(dd.x, dd.y, pc.x + pc.x, ba);
      tB[pm] = make_float2(pu.x + pu.x, bb);
    }
  }
  __syncthreads();

  const int sub = tid & 3;
  const int grp = tid >> 2;
  const int pbase = sub * 9;

  float pdx[8], pdy[8], paa[8], pba[8], pab[8], pbb[8];
  #pragma unroll
  for (int k = 0; k < 8; k++) {
    float4 A = tA[pbase + k];
    c32 Bv = tB[pbase + k];
    pdx[k] = A.x; pdy[k] = A.y; paa[k] = A.z; pba[k] = A.w;
    pab[k] = Bv.x; pbb[k] = Bv.y;
  }

  float U1x[8], U2x[8];
  #pragma unroll
  for (int k = 0; k < 8; k++) { U1x[k] = 0.0f; U2x[k] = 0.0f; }

  #pragma unroll 2
  for (int it = 0; it < 16; it++) {
    const int j = base + (it << 7) + grp;
    float rev = (float)j * (1.0f/8192.0f);
    float zx = __builtin_amdgcn_cosf(rev);
    float zy = __builtin_amdgcn_sinf(rev);
    float t2zy = zy + zy;

    float iwxA[8], iwyA[8];
    float Px = 0.0f, Py = 0.0f, Qx = 0.0f, Qy = 0.0f;
    float Rx = 0.0f, Ry = 0.0f, Sx = 0.0f, Sy = 0.0f;
    #pragma unroll
    for (int k = 0; k < 8; k++) {
      float dxx = zx - pdx[k];
      float dy1 = zy - pdy[k];
      float dy2 = zy + pdy[k];
      float xx  = dxx*dxx;
      float p12 = dy1*dy2;
      float wvx = xx - p12;
      float wvyn = dxx*t2zy;
      float den = fmaf(wvx, wvx, wvyn*wvyn);
      float ip  = frcp(den);
      float iwx = wvx*ip;
      float iwy = -wvyn*ip;
      iwxA[k] = iwx; iwyA[k] = iwy;
      Px = fmaf(paa[k], iwx, Px); Py = fmaf(paa[k], iwy, Py);
      Qx = fmaf(pba[k], iwx, Qx); Qy = fmaf(pba[k], iwy, Qy);
      Rx = fmaf(pab[k], iwx, Rx); Ry = fmaf(pab[k], iwy, Ry);
      Sx = fmaf(pbb[k], iwx, Sx); Sy = fmaf(pbb[k], iwy, Sy);
    }
    float ax = fmaf(zx, Px, fmaf(-zy, Py, -Qx));
    float ay = fmaf(zx, Py, fmaf( zy, Px, -Qy));
    float bx = fmaf(zx, Rx, fmaf(-zy, Ry, -Sx));
    float by = fmaf(zx, Ry, fmaf( zy, Rx, -Sy));
    ax += dpp_xor1(ax); ax += dpp_xor2(ax);
    ay += dpp_xor1(ay); ay += dpp_xor2(ay);
    bx += dpp_xor1(bx); bx += dpp_xor2(bx);
    by += dpp_xor1(by); by += dpp_xor2(by);
    float denq = 1.0f + bx, deny = by;
    float idn = frcp(fmaf(denq, denq, deny*deny));
    float tx = (ax*denq + ay*deny)*idn;
    float ty = (ay*denq - ax*deny)*idn;
    float qx = zx*tx - zy*ty;
    float qy = zx*ty + zy*tx;
    if (j == 0) { qx *= 0.5f; qy *= 0.5f; }
    float qzx = qx*zx - qy*zy;
    float qzy = fmaf(qx, zy, qy*zx);
    #pragma unroll
    for (int k = 0; k < 8; k++) {
      float iwx = iwxA[k], iwy = iwyA[k];
      U1x[k] = fmaf(qx,  iwx, fmaf(-qy,  iwy, U1x[k]));
      U2x[k] = fmaf(qzx, iwx, fmaf(-qzy, iwy, U2x[k]));
    }
  }

  float ssx[8], ssy[8];
  #pragma unroll
  for (int k = 0; k < 8; k++) {
    ssx[k] = fmaf(-(pdx[k] + pdx[k]), U1x[k], U2x[k] + U2x[k]);
    ssy[k] = (pdy[k] + pdy[k]) * U1x[k];
  }

  #pragma unroll
  for (int off = 4; off <= 32; off <<= 1) {
    #pragma unroll
    for (int k = 0; k < 8; k++) {
      ssx[k] += __shfl_xor(ssx[k], off, 64);
      ssy[k] += __shfl_xor(ssy[k], off, 64);
    }
  }
  const int lane = tid & 63;
  const int wv = tid >> 6;
  if (lane < 4) {
    #pragma unroll
    for (int k = 0; k < 8; k++) {
      red[wv*64 + lane*16 + 2*k]     = ssx[k];
      red[wv*64 + lane*16 + 2*k + 1] = ssy[k];
    }
  }
  __syncthreads();

  if (tid < 64) {
    float t = 0.0f;
    #pragma unroll
    for (int w = 0; w < 8; w++) t += red[w*64 + tid];
    Sws[bid*64 + tid] = t;    // layout: [h][half][2m+bit]
  }
}

// ---------------- K2: combine + deferred poly-Cauchy + irfft (r18) --------
__global__ __launch_bounds__(1024, 2)
void ssk_B(const float* __restrict__ log_dt, const float* __restrict__ invwr,
           const float* __restrict__ wim, const float* __restrict__ Pin,
           const float* __restrict__ Bin, const float* __restrict__ Cin,
           const float* __restrict__ Sws, c32* __restrict__ out)
{
  __shared__ __align__(16) c32 Xs[4098];   // spectrum / FFT ping
  __shared__ __align__(16) c32 Zs[4096];   // packed seq / FFT pong
  __shared__ __align__(16) float4 cs1_s[NN];  // (aw, tnw, a00, b00)
  __shared__ __align__(16) float4 cs2_s[NN];  // (a01, b01, a10, b10)
  __shared__ c32 cs3_s[NN];                   // (a11, b11)
  const int h = blockIdx.x;
  const int tid = threadIdx.x;

  // ---- per-head algebra redo + combine (wave 0) ----
  if (tid < 64) {
    const int n = tid & 31;
    const bool cj = tid >= 32;
    const float dt = expf(log_dt[h]);
    float wr = -expf(invwr[h*NN + n]);
    float wi = wim[h*NN + n];
    if (cj) wi = -wi;
    const float tdt = 2.0f / dt;
    float dr = tdt - wr, di = -wi;
    float invd = 1.0f / (dr*dr + di*di);
    c32 D = make_float2(dr*invd, -di*invd);
    c32 E = make_float2(tdt + wr, wi);
    c32 Pf = make_float2(Pin[(h*NN+n)*2], Pin[(h*NN+n)*2+1]);
    if (cj) Pf.y = -Pf.y;
    c32 Cf = make_float2(Cin[(h*NN+n)*2], Cin[(h*NN+n)*2+1]);
    if (cj) Cf.y = -Cf.y;
    float rm = (Pf.x*Pf.x + Pf.y*Pf.y) * D.x;
    #pragma unroll
    for (int off = 32; off >= 1; off >>= 1) rm += __shfl_xor(rm, off, 64);
    rm += 1.0f;
    c32 Rc = cmul(cconjf(Pf), D);
    float invrm = 1.0f / rm;
    Rc.x *= invrm; Rc.y *= invrm;
    c32 RP = cmul(Rc, Pf);
    #pragma unroll
    for (int off = 32; off >= 1; off >>= 1) {
      RP.x += __shfl_xor(RP.x, off, 64);
      RP.y += __shfl_xor(RP.y, off, 64);
    }
    c32 Q2 = cconjf(Pf);
    c32 s  = csub(cmul(Rc, E), cmul(RP, Q2));
    c32 u  = cadd(Q2, s);
    c32 dd = cmul(D, E);
    c32 pp = cmul(D, Pf);
    c32 pc = cmul(pp, Cf);
    c32 pu = cmul(pp, u);

    // z = -1 node: g = conj(-1-d)/|.|^2 ; a,b real (conj-pair fold)
    float dxxn = -1.0f - dd.x;
    float nn1 = fmaf(dxxn, dxxn, dd.y*dd.y);
    float ii = frcp(nn1);
    float glxn = dxxn*ii, glyn = dd.y*ii;
    float aterm = 2.0f*(pc.x*glxn - pc.y*glyn);
    float bterm = 2.0f*(pu.x*glxn - pu.y*glyn);
    #pragma unroll
    for (int off = 16; off >= 1; off >>= 1) {
      aterm += __shfl_xor(aterm, off, 64);
      bterm += __shfl_xor(bterm, off, 64);
    }

    if (tid < 32) {
      const int m = tid;
      c32 dL = dd;
      #pragma unroll
      for (int i2 = 0; i2 < 13; i2++) dL = cmul(dL, dL);
      c32 S;
      S.x = Sws[h*128 + 2*m]     + Sws[h*128 + 64 + 2*m];
      S.y = Sws[h*128 + 2*m + 1] + Sws[h*128 + 64 + 2*m + 1];
      float qn = -aterm * frcp(1.0f + bterm) * 0.5f;
      S.x += qn * 2.0f * glxn;
      S.y += qn * 2.0f * glyn;
      c32 y = cmul(Cf, dL);
      c32 uS = cmul(u, S);
      y.x -= uS.x * (1.0f/8192.0f);
      y.y -= uS.y * (1.0f/8192.0f);
      c32 Ct = csub(Cf, y);
      c32 Bc = make_float2(Bin[(h*NN+m)*2], Bin[(h*NN+m)*2+1]);
      c32 Qc = cconjf(Pf);
      c32 v00 = cmul(Bc, Ct), v01 = cmul(Bc, Qc), v10 = cmul(Pf, Ct), v11 = cmul(Pf, Qc);
      float wx = wr*dt, wy = wi*dt;
      float aw = fmaf(wx, wx, wy*wy);
      float tnw = -(wx + wx);
      float td = dt + dt;
      float a00 = td*v00.x, b00 = td*(v00.x*wx + v00.y*wy);
      float a01 = td*v01.x, b01 = td*(v01.x*wx + v01.y*wy);
      float a10 = td*v10.x, b10 = td*(v10.x*wx + v10.y*wy);
      float a11 = td*v11.x, b11 = td*(v11.x*wx + v11.y*wy);
      cs1_s[m] = make_float4(aw, tnw, a00, b00);
      cs2_s[m] = make_float4(a01, b01, a10, b10);
      cs3_s[m] = make_float2(a11, b11);
      // Nyquist X[4096] = sum Re(v00*dt)
      float s00 = v00.x * dt;
      #pragma unroll
      for (int off = 16; off >= 1; off >>= 1) s00 += __shfl_xor(s00, off, 64);
      if (m == 0) Xs[MF] = make_float2(s00, 0.0f);
    }
  }
  __syncthreads();

  // ---- deferred poly Cauchy at z_j = 2i tan(pi j/L), 4 nodes/thread ----
  {
    float Tq[4], t2[4], t2sq[4];
    c32 A0[4], B0[4], A1[4], B1[4], A2[4], B2[4], A3[4], B3[4];
    #pragma unroll
    for (int q = 0; q < 4; q++) {
      int j = tid + (q << 10);
      float rev = (float)j * (1.0f/16384.0f);
      float sn = __builtin_amdgcn_sinf(rev);
      float cs = __builtin_amdgcn_cosf(rev);
      float T = sn * frcp(cs);
      Tq[q] = T; t2[q] = 2.0f*T; t2sq[q] = t2[q]*t2[q];
      A0[q] = make_float2(0,0); B0[q] = make_float2(0,0);
      A1[q] = make_float2(0,0); B1[q] = make_float2(0,0);
      A2[q] = make_float2(0,0); B2[q] = make_float2(0,0);
      A3[q] = make_float2(0,0); B3[q] = make_float2(0,0);
    }
    #pragma unroll 2
    for (int n = 0; n < NN; n++) {
      float4 C1 = cs1_s[n];   // aw, tnw, a00, b00
      float4 C2 = cs2_s[n];   // a01, b01, a10, b10
      c32   C3 = cs3_s[n];    // a11, b11
      #pragma unroll
      for (int q = 0; q < 4; q++) {
        float wvx = C1.x - t2sq[q];
        float wvy = C1.y * t2[q];
        float r = frcp(fmaf(wvx, wvx, wvy*wvy));
        float iwx = wvx*r;
        float iwy = -wvy*r;
        A0[q].x = fmaf(C1.z, iwx, A0[q].x); A0[q].y = fmaf(C1.z, iwy, A0[q].y);
        B0[q].x = fmaf(C1.w, iwx, B0[q].x); B0[q].y = fmaf(C1.w, iwy, B0[q].y);
        A1[q].x = fmaf(C2.x, iwx, A1[q].x); A1[q].y = fmaf(C2.x, iwy, A1[q].y);
        B1[q].x = fmaf(C2.y, iwx, B1[q].x); B1[q].y = fmaf(C2.y, iwy, B1[q].y);
        A2[q].x = fmaf(C2.z, iwx, A2[q].x); A2[q].y = fmaf(C2.z, iwy, A2[q].y);
        B2[q].x = fmaf(C2.w, iwx, B2[q].x); B2[q].y = fmaf(C2.w, iwy, B2[q].y);
        A3[q].x = fmaf(C3.x, iwx, A3[q].x); A3[q].y = fmaf(C3.x, iwy, A3[q].y);
        B3[q].x = fmaf(C3.y, iwx, B3[q].x); B3[q].y = fmaf(C3.y, iwy, B3[q].y);
      }
    }
    #pragma unroll
    for (int q = 0; q < 4; q++) {
      float tt = t2[q];
      c32 a00 = make_float2(fmaf(-tt, A0[q].y, -B0[q].x), fmaf(tt, A0[q].x, -B0[q].y));
      c32 a01 = make_float2(fmaf(-tt, A1[q].y, -B1[q].x), fmaf(tt, A1[q].x, -B1[q].y));
      c32 a10 = make_float2(fmaf(-tt, A2[q].y, -B2[q].x), fmaf(tt, A2[q].x, -B2[q].y));
      c32 a11 = make_float2(fmaf(-tt, A3[q].y, -B3[q].x), fmaf(tt, A3[q].x, -B3[q].y));
      float denx = 1.0f + a11.x, deny = a11.y;
      float idn = frcp(fmaf(denx, denx, deny*deny));
      c32 invden = make_float2(denx*idn, -deny*idn);
      c32 kf = csub(a00, cmul(cmul(a01, a10), invden));
      float T = Tq[q];
      Xs[tid + (q << 10)] = make_float2(kf.x - T*kf.y, kf.y + T*kf.x);  // *(1+iT)
    }
  }
  __syncthreads();

  // ---- real-irfft packing: Z[k] = (E[k] + i*O[k]) / MF ----
  const float invM = 1.0f / (float)MF;
  #pragma unroll
  for (int qq = 0; qq < 4; qq++) {
    int k = tid + (qq << 10);
    c32 Xk = Xs[k];
    c32 Xm = Xs[MF - k];
    float Ex = 0.5f*(Xk.x + Xm.x), Ey = 0.5f*(Xk.y - Xm.y);
    float Ox = 0.5f*(Xk.x - Xm.x), Oy = 0.5f*(Xk.y + Xm.y);
    float rev = (float)k * (1.0f/8192.0f);
    float cs = __builtin_amdgcn_cosf(rev);
    float sn = __builtin_amdgcn_sinf(rev);
    float Orx = Ox*cs - Oy*sn;
    float Ory = Ox*sn + Oy*cs;
    Zs[k] = make_float2((Ex - Ory)*invM, (Ey + Orx)*invM);
  }
  __syncthreads();

  // ---- 6-stage radix-4 Stockham inverse FFT (twiddle sign +) ----
  c32* srcf = Zs;
  c32* dstf = Xs;
  int sstride = 1;
  #pragma unroll
  for (int st = 0; st < 6; st++) {
    int jm = tid & ~(sstride - 1);
    float rev = (float)jm * (1.0f/4096.0f);
    float sn = __builtin_amdgcn_sinf(rev);
    float cs = __builtin_amdgcn_cosf(rev);
    c32 w1 = make_float2(cs, sn);
    c32 w2 = cmul(w1, w1);
    c32 w3 = cmul(w2, w1);
    c32 a = srcf[tid];
    c32 b = srcf[tid + 1024];
    c32 c = srcf[tid + 2048];
    c32 d = srcf[tid + 3072];
    c32 apc = cadd(a, c), amc = csub(a, c);
    c32 bpd = cadd(b, d), bmd = csub(b, d);
    int wb = tid + 3*jm;
    dstf[wb] = cadd(apc, bpd);
    dstf[wb + sstride]   = cmul(w1, make_float2(amc.x - bmd.y, amc.y + bmd.x));
    dstf[wb + 2*sstride] = cmul(w2, csub(apc, bpd));
    dstf[wb + 3*sstride] = cmul(w3, make_float2(amc.x + bmd.y, amc.y - bmd.x));
    __syncthreads();
    c32* t = srcf; srcf = dstf; dstf = t;
    sstride <<= 2;
  }

  // even stage count -> result in Zs (= srcf); z[m] = (x[2m], x[2m+1])
  {
    float4* o4 = (float4*)(out + (size_t)h*MF);
    const float4* s4 = (const float4*)srcf;
    o4[tid] = s4[tid];
    o4[tid + 1024] = s4[tid + 1024];
  }
}

extern "C" void kernel_launch(void* const* d_in, const int* in_sizes, int n_in,
                              void* d_out, int out_size, void* d_ws, size_t ws_size,
                              hipStream_t stream) {
  const float* log_dt = (const float*)d_in[0];
  const float* invwr  = (const float*)d_in[1];
  const float* wimag  = (const float*)d_in[2];
  const float* P      = (const float*)d_in[3];
  const float* B      = (const float*)d_in[4];
  const float* C      = (const float*)d_in[5];
  float* Sws = (float*)d_ws;                 // 512 blocks * 64 floats = 128 KB
  c32*   out = (c32*)d_out;                  // (H,8192) fp32 = (H,4096) c32
  (void)in_sizes; (void)n_in; (void)out_size; (void)ws_size;

  ssk_S<<<2*HH, 512, 0, stream>>>(log_dt, invwr, wimag, P, C, Sws);
  ssk_B<<<HH, 1024, 0, stream>>>(log_dt, invwr, wimag, P, B, C, Sws, out);
}

// Round 20
// 54.096 us; speedup vs baseline: 1.0409x; 1.0409x over previous
//
#include <hip/hip_runtime.h>

// SSKernelNPLR, 2-kernel pipeline. H=256, N=32 (M=64 conj-extended), R=1, L=8192.
// K1 ssk_S (grid 512, 512 thr, lb(512,2) -> cap 128): contour, quad node
//    groups, register-resident params, deferred a,b, DPP quad reduce,
//    U1/U2 real-part deferral. Sws [h][half][2m+bit].  (r16-verified)
// K2 ssk_B (grid 256, 1024 thr, lb(1024,2) -> cap 128; grid-capped 16 waves/CU):
//    combine (2 halves) + C~ + poly-Cauchy at z = 2i tan(pi j/L) with DEFERRED
//    A/B accumulation (A = sum alpha iw, B = sum beta iw; acc = -B + i t2 A,
//    r17-verified); Woodbury + (1+iT); real-irfft packing; 6-stage radix-4
//    Stockham inverse FFT -> out.  (r18-verified best: 54.2 us)

#define HH 256
#define NN 32
#define MF 4096

typedef float2 c32;

__device__ __forceinline__ c32 cmul(c32 a, c32 b){ return make_float2(a.x*b.x - a.y*b.y, a.x*b.y + a.y*b.x); }
__device__ __forceinline__ c32 cadd(c32 a, c32 b){ return make_float2(a.x+b.x, a.y+b.y); }
__device__ __forceinline__ c32 csub(c32 a, c32 b){ return make_float2(a.x-b.x, a.y-b.y); }
__device__ __forceinline__ c32 cconjf(c32 a){ return make_float2(a.x, -a.y); }
__device__ __forceinline__ float frcp(float x){ return __builtin_amdgcn_rcpf(x); }

// DPP quad_perm lane swaps (VALU pipe): xor1 = [1,0,3,2], xor2 = [2,3,0,1]
__device__ __forceinline__ float dpp_xor1(float x){
  return __int_as_float(__builtin_amdgcn_update_dpp(0, __float_as_int(x), 0xB1, 0xF, 0xF, true));
}
__device__ __forceinline__ float dpp_xor2(float x){
  return __int_as_float(__builtin_amdgcn_update_dpp(0, __float_as_int(x), 0x4E, 0xF, 0xF, true));
}

// ---------------- K1: contour (r16-verified, unchanged) --------------------
__global__ __launch_bounds__(512, 2)
void ssk_S(const float* __restrict__ log_dt, const float* __restrict__ invwr,
           const float* __restrict__ wim, const float* __restrict__ Pin,
           const float* __restrict__ Cin, float* __restrict__ Sws)
{
  __shared__ __align__(16) float4 tA[36];   // (d.x, d.y, alpha_a, beta_a), pad m+(m>>3)
  __shared__ c32 tB[36];                    // (alpha_b, beta_b)
  __shared__ float red[8*64];               // [wave][component]
  const int bid = blockIdx.x;
  const int h = bid >> 1;
  const int base = (bid & 1) << 11;         // 0 or 2048
  const int tid = threadIdx.x;

  if (tid < 64) {
    const int n = tid & 31;
    const bool cj = tid >= 32;
    const float dt = expf(log_dt[h]);
    float wr = -expf(invwr[h*NN + n]);
    float wi = wim[h*NN + n];
    if (cj) wi = -wi;
    const float tdt = 2.0f / dt;
    float dr = tdt - wr, di = -wi;
    float invd = 1.0f / (dr*dr + di*di);
    c32 D = make_float2(dr*invd, -di*invd);   // 1/(2/dt - w)
    c32 E = make_float2(tdt + wr, wi);        // 2/dt + w
    c32 Pf = make_float2(Pin[(h*NN+n)*2], Pin[(h*NN+n)*2+1]);
    if (cj) Pf.y = -Pf.y;
    c32 Cf = make_float2(Cin[(h*NN+n)*2], Cin[(h*NN+n)*2+1]);
    if (cj) Cf.y = -Cf.y;
    float rm = (Pf.x*Pf.x + Pf.y*Pf.y) * D.x;
    #pragma unroll
    for (int off = 32; off >= 1; off >>= 1) rm += __shfl_xor(rm, off, 64);
    rm += 1.0f;
    c32 Rc = cmul(cconjf(Pf), D);
    float invrm = 1.0f / rm;
    Rc.x *= invrm; Rc.y *= invrm;
    c32 RP = cmul(Rc, Pf);
    #pragma unroll
    for (int off = 32; off >= 1; off >>= 1) {
      RP.x += __shfl_xor(RP.x, off, 64);
      RP.y += __shfl_xor(RP.y, off, 64);
    }
    c32 Q2 = cconjf(Pf);
    c32 s  = csub(cmul(Rc, E), cmul(RP, Q2));
    c32 u  = cadd(Q2, s);                     // dA = diag(dd) - pp u^T
    c32 dd = cmul(D, E);
    c32 pp = cmul(D, Pf);
    c32 pc = cmul(pp, Cf);
    c32 pu = cmul(pp, u);
    if (tid < 32) {
      const int pm = tid + (tid >> 3);
      float ba = 2.0f*(pc.x*dd.x + pc.y*dd.y);
      float bb = 2.0f*(pu.x*dd.x + pu.y*dd.y);
      tA[pm] = make_float4(dd.x, dd.y, pc.x + pc.x, ba);
      tB[pm] = make_float2(pu.x + pu.x, bb);
    }
  }
  __syncthreads();

  const int sub = tid & 3;
  const int grp = tid >> 2;
  const int pbase = sub * 9;

  float pdx[8], pdy[8], paa[8], pba[8], pab[8], pbb[8];
  #pragma unroll
  for (int k = 0; k < 8; k++) {
    float4 A = tA[pbase + k];
    c32 Bv = tB[pbase + k];
    pdx[k] = A.x; pdy[k] = A.y; paa[k] = A.z; pba[k] = A.w;
    pab[k] = Bv.x; pbb[k] = Bv.y;
  }

  float U1x[8], U2x[8];
  #pragma unroll
  for (int k = 0; k < 8; k++) { U1x[k] = 0.0f; U2x[k] = 0.0f; }

  for (int it = 0; it < 16; it++) {
    const int j = base + (it << 7) + grp;
    float rev = (float)j * (1.0f/8192.0f);
    float zx = __builtin_amdgcn_cosf(rev);
    float zy = __builtin_amdgcn_sinf(rev);
    float t2zy = zy + zy;

    float iwxA[8], iwyA[8];
    float Px = 0.0f, Py = 0.0f, Qx = 0.0f, Qy = 0.0f;
    float Rx = 0.0f, Ry = 0.0f, Sx = 0.0f, Sy = 0.0f;
    #pragma unroll
    for (int k = 0; k < 8; k++) {
      float dxx = zx - pdx[k];
      float dy1 = zy - pdy[k];
      float dy2 = zy + pdy[k];
      float xx  = dxx*dxx;
      float p12 = dy1*dy2;
      float wvx = xx - p12;
      float wvyn = dxx*t2zy;
      float den = fmaf(wvx, wvx, wvyn*wvyn);
      float ip  = frcp(den);
      float iwx = wvx*ip;
      float iwy = -wvyn*ip;
      iwxA[k] = iwx; iwyA[k] = iwy;
      Px = fmaf(paa[k], iwx, Px); Py = fmaf(paa[k], iwy, Py);
      Qx = fmaf(pba[k], iwx, Qx); Qy = fmaf(pba[k], iwy, Qy);
      Rx = fmaf(pab[k], iwx, Rx); Ry = fmaf(pab[k], iwy, Ry);
      Sx = fmaf(pbb[k], iwx, Sx); Sy = fmaf(pbb[k], iwy, Sy);
    }
    float ax = fmaf(zx, Px, fmaf(-zy, Py, -Qx));
    float ay = fmaf(zx, Py, fmaf( zy, Px, -Qy));
    float bx = fmaf(zx, Rx, fmaf(-zy, Ry, -Sx));
    float by = fmaf(zx, Ry, fmaf( zy, Rx, -Sy));
    ax += dpp_xor1(ax); ax += dpp_xor2(ax);
    ay += dpp_xor1(ay); ay += dpp_xor2(ay);
    bx += dpp_xor1(bx); bx += dpp_xor2(bx);
    by += dpp_xor1(by); by += dpp_xor2(by);
    float denq = 1.0f + bx, deny = by;
    float idn = frcp(fmaf(denq, denq, deny*deny));
    float tx = (ax*denq + ay*deny)*idn;
    float ty = (ay*denq - ax*deny)*idn;
    float qx = zx*tx - zy*ty;
    float qy = zx*ty + zy*tx;
    if (j == 0) { qx *= 0.5f; qy *= 0.5f; }
    float qzx = qx*zx - qy*zy;
    float qzy = fmaf(qx, zy, qy*zx);
    #pragma unroll
    for (int k = 0; k < 8; k++) {
      float iwx = iwxA[k], iwy = iwyA[k];
      U1x[k] = fmaf(qx,  iwx, fmaf(-qy,  iwy, U1x[k]));
      U2x[k] = fmaf(qzx, iwx, fmaf(-qzy, iwy, U2x[k]));
    }
  }

  float ssx[8], ssy[8];
  #pragma unroll
  for (int k = 0; k < 8; k++) {
    ssx[k] = fmaf(-(pdx[k] + pdx[k]), U1x[k], U2x[k] + U2x[k]);
    ssy[k] = (pdy[k] + pdy[k]) * U1x[k];
  }

  #pragma unroll
  for (int off = 4; off <= 32; off <<= 1) {
    #pragma unroll
    for (int k = 0; k < 8; k++) {
      ssx[k] += __shfl_xor(ssx[k], off, 64);
      ssy[k] += __shfl_xor(ssy[k], off, 64);
    }
  }
  const int lane = tid & 63;
  const int wv = tid >> 6;
  if (lane < 4) {
    #pragma unroll
    for (int k = 0; k < 8; k++) {
      red[wv*64 + lane*16 + 2*k]     = ssx[k];
      red[wv*64 + lane*16 + 2*k + 1] = ssy[k];
    }
  }
  __syncthreads();

  if (tid < 64) {
    float t = 0.0f;
    #pragma unroll
    for (int w = 0; w < 8; w++) t += red[w*64 + tid];
    Sws[bid*64 + tid] = t;    // layout: [h][half][2m+bit]
  }
}

// ---------------- K2: combine + deferred poly-Cauchy + irfft --------------
__global__ __launch_bounds__(1024, 2)
void ssk_B(const float* __restrict__ log_dt, const float* __restrict__ invwr,
           const float* __restrict__ wim, const float* __restrict__ Pin,
           const float* __restrict__ Bin, const float* __restrict__ Cin,
           const float* __restrict__ Sws, c32* __restrict__ out)
{
  __shared__ __align__(16) c32 Xs[4098];   // spectrum / FFT ping
  __shared__ __align__(16) c32 Zs[4096];   // packed seq / FFT pong
  __shared__ __align__(16) float4 cs1_s[NN];  // (aw, tnw, a00, b00)
  __shared__ __align__(16) float4 cs2_s[NN];  // (a01, b01, a10, b10)
  __shared__ c32 cs3_s[NN];                   // (a11, b11)
  const int h = blockIdx.x;
  const int tid = threadIdx.x;

  // ---- per-head algebra redo + combine (wave 0) ----
  if (tid < 64) {
    const int n = tid & 31;
    const bool cj = tid >= 32;
    const float dt = expf(log_dt[h]);
    float wr = -expf(invwr[h*NN + n]);
    float wi = wim[h*NN + n];
    if (cj) wi = -wi;
    const float tdt = 2.0f / dt;
    float dr = tdt - wr, di = -wi;
    float invd = 1.0f / (dr*dr + di*di);
    c32 D = make_float2(dr*invd, -di*invd);
    c32 E = make_float2(tdt + wr, wi);
    c32 Pf = make_float2(Pin[(h*NN+n)*2], Pin[(h*NN+n)*2+1]);
    if (cj) Pf.y = -Pf.y;
    c32 Cf = make_float2(Cin[(h*NN+n)*2], Cin[(h*NN+n)*2+1]);
    if (cj) Cf.y = -Cf.y;
    float rm = (Pf.x*Pf.x + Pf.y*Pf.y) * D.x;
    #pragma unroll
    for (int off = 32; off >= 1; off >>= 1) rm += __shfl_xor(rm, off, 64);
    rm += 1.0f;
    c32 Rc = cmul(cconjf(Pf), D);
    float invrm = 1.0f / rm;
    Rc.x *= invrm; Rc.y *= invrm;
    c32 RP = cmul(Rc, Pf);
    #pragma unroll
    for (int off = 32; off >= 1; off >>= 1) {
      RP.x += __shfl_xor(RP.x, off, 64);
      RP.y += __shfl_xor(RP.y, off, 64);
    }
    c32 Q2 = cconjf(Pf);
    c32 s  = csub(cmul(Rc, E), cmul(RP, Q2));
    c32 u  = cadd(Q2, s);
    c32 dd = cmul(D, E);
    c32 pp = cmul(D, Pf);
    c32 pc = cmul(pp, Cf);
    c32 pu = cmul(pp, u);

    // z = -1 node: g = conj(-1-d)/|.|^2 ; a,b real (conj-pair fold)
    float dxxn = -1.0f - dd.x;
    float nn1 = fmaf(dxxn, dxxn, dd.y*dd.y);
    float ii = frcp(nn1);
    float glxn = dxxn*ii, glyn = dd.y*ii;
    float aterm = 2.0f*(pc.x*glxn - pc.y*glyn);
    float bterm = 2.0f*(pu.x*glxn - pu.y*glyn);
    #pragma unroll
    for (int off = 16; off >= 1; off >>= 1) {
      aterm += __shfl_xor(aterm, off, 64);
      bterm += __shfl_xor(bterm, off, 64);
    }

    if (tid < 32) {
      const int m = tid;
      c32 dL = dd;
      #pragma unroll
      for (int i2 = 0; i2 < 13; i2++) dL = cmul(dL, dL);
      c32 S;
      S.x = Sws[h*128 + 2*m]     + Sws[h*128 + 64 + 2*m];
      S.y = Sws[h*128 + 2*m + 1] + Sws[h*128 + 64 + 2*m + 1];
      float qn = -aterm * frcp(1.0f + bterm) * 0.5f;
      S.x += qn * 2.0f * glxn;
      S.y += qn * 2.0f * glyn;
      c32 y = cmul(Cf, dL);
      c32 uS = cmul(u, S);
      y.x -= uS.x * (1.0f/8192.0f);
      y.y -= uS.y * (1.0f/8192.0f);
      c32 Ct = csub(Cf, y);
      c32 Bc = make_float2(Bin[(h*NN+m)*2], Bin[(h*NN+m)*2+1]);
      c32 Qc = cconjf(Pf);
      c32 v00 = cmul(Bc, Ct), v01 = cmul(Bc, Qc), v10 = cmul(Pf, Ct), v11 = cmul(Pf, Qc);
      float wx = wr*dt, wy = wi*dt;
      float aw = fmaf(wx, wx, wy*wy);
      float tnw = -(wx + wx);
      float td = dt + dt;
      float a00 = td*v00.x, b00 = td*(v00.x*wx + v00.y*wy);
      float a01 = td*v01.x, b01 = td*(v01.x*wx + v01.y*wy);
      float a10 = td*v10.x, b10 = td*(v10.x*wx + v10.y*wy);
      float a11 = td*v11.x, b11 = td*(v11.x*wx + v11.y*wy);
      cs1_s[m] = make_float4(aw, tnw, a00, b00);
      cs2_s[m] = make_float4(a01, b01, a10, b10);
      cs3_s[m] = make_float2(a11, b11);
      // Nyquist X[4096] = sum Re(v00*dt)
      float s00 = v00.x * dt;
      #pragma unroll
      for (int off = 16; off >= 1; off >>= 1) s00 += __shfl_xor(s00, off, 64);
      if (m == 0) Xs[MF] = make_float2(s00, 0.0f);
    }
  }
  __syncthreads();

  // ---- deferred poly Cauchy at z_j = 2i tan(pi j/L), 4 nodes/thread ----
  {
    float Tq[4], t2[4], t2sq[4];
    c32 A0[4], B0[4], A1[4], B1[4], A2[4], B2[4], A3[4], B3[4];
    #pragma unroll
    for (int q = 0; q < 4; q++) {
      int j = tid + (q << 10);
      float rev = (float)j * (1.0f/16384.0f);
      float sn = __builtin_amdgcn_sinf(rev);
      float cs = __builtin_amdgcn_cosf(rev);
      float T = sn * frcp(cs);
      Tq[q] = T; t2[q] = 2.0f*T; t2sq[q] = t2[q]*t2[q];
      A0[q] = make_float2(0,0); B0[q] = make_float2(0,0);
      A1[q] = make_float2(0,0); B1[q] = make_float2(0,0);
      A2[q] = make_float2(0,0); B2[q] = make_float2(0,0);
      A3[q] = make_float2(0,0); B3[q] = make_float2(0,0);
    }
    #pragma unroll 2
    for (int n = 0; n < NN; n++) {
      float4 C1 = cs1_s[n];   // aw, tnw, a00, b00
      float4 C2 = cs2_s[n];   // a01, b01, a10, b10
      c32   C3 = cs3_s[n];    // a11, b11
      #pragma unroll
      for (int q = 0; q < 4; q++) {
        float wvx = C1.x - t2sq[q];
        float wvy = C1.y * t2[q];
        float r = frcp(fmaf(wvx, wvx, wvy*wvy));
        float iwx = wvx*r;
        float iwy = -wvy*r;
        A0[q].x = fmaf(C1.z, iwx, A0[q].x); A0[q].y = fmaf(C1.z, iwy, A0[q].y);
        B0[q].x = fmaf(C1.w, iwx, B0[q].x); B0[q].y = fmaf(C1.w, iwy, B0[q].y);
        A1[q].x = fmaf(C2.x, iwx, A1[q].x); A1[q].y = fmaf(C2.x, iwy, A1[q].y);
        B1[q].x = fmaf(C2.y, iwx, B1[q].x); B1[q].y = fmaf(C2.y, iwy, B1[q].y);
        A2[q].x = fmaf(C2.z, iwx, A2[q].x); A2[q].y = fmaf(C2.z, iwy, A2[q].y);
        B2[q].x = fmaf(C2.w, iwx, B2[q].x); B2[q].y = fmaf(C2.w, iwy, B2[q].y);
        A3[q].x = fmaf(C3.x, iwx, A3[q].x); A3[q].y = fmaf(C3.x, iwy, A3[q].y);
        B3[q].x = fmaf(C3.y, iwx, B3[q].x); B3[q].y = fmaf(C3.y, iwy, B3[q].y);
      }
    }
    #pragma unroll
    for (int q = 0; q < 4; q++) {
      float tt = t2[q];
      c32 a00 = make_float2(fmaf(-tt, A0[q].y, -B0[q].x), fmaf(tt, A0[q].x, -B0[q].y));
      c32 a01 = make_float2(fmaf(-tt, A1[q].y, -B1[q].x), fmaf(tt, A1[q].x, -B1[q].y));
      c32 a10 = make_float2(fmaf(-tt, A2[q].y, -B2[q].x), fmaf(tt, A2[q].x, -B2[q].y));
      c32 a11 = make_float2(fmaf(-tt, A3[q].y, -B3[q].x), fmaf(tt, A3[q].x, -B3[q].y));
      float denx = 1.0f + a11.x, deny = a11.y;
      float idn = frcp(fmaf(denx, denx, deny*deny));
      c32 invden = make_float2(denx*idn, -deny*idn);
      c32 kf = csub(a00, cmul(cmul(a01, a10), invden));
      float T = Tq[q];
      Xs[tid + (q << 10)] = make_float2(kf.x - T*kf.y, kf.y + T*kf.x);  // *(1+iT)
    }
  }
  __syncthreads();

  // ---- real-irfft packing: Z[k] = (E[k] + i*O[k]) / MF ----
  const float invM = 1.0f / (float)MF;
  #pragma unroll
  for (int qq = 0; qq < 4; qq++) {
    int k = tid + (qq << 10);
    c32 Xk = Xs[k];
    c32 Xm = Xs[MF - k];
    float Ex = 0.5f*(Xk.x + Xm.x), Ey = 0.5f*(Xk.y - Xm.y);
    float Ox = 0.5f*(Xk.x - Xm.x), Oy = 0.5f*(Xk.y + Xm.y);
    float rev = (float)k * (1.0f/8192.0f);
    float cs = __builtin_amdgcn_cosf(rev);
    float sn = __builtin_amdgcn_sinf(rev);
    float Orx = Ox*cs - Oy*sn;
    float Ory = Ox*sn + Oy*cs;
    Zs[k] = make_float2((Ex - Ory)*invM, (Ey + Orx)*invM);
  }
  __syncthreads();

  // ---- 6-stage radix-4 Stockham inverse FFT (twiddle sign +) ----
  c32* srcf = Zs;
  c32* dstf = Xs;
  int sstride = 1;
  #pragma unroll
  for (int st = 0; st < 6; st++) {
    int jm = tid & ~(sstride - 1);
    float rev = (float)jm * (1.0f/4096.0f);
    float sn = __builtin_amdgcn_sinf(rev);
    float cs = __builtin_amdgcn_cosf(rev);
    c32 w1 = make_float2(cs, sn);
    c32 w2 = cmul(w1, w1);
    c32 w3 = cmul(w2, w1);
    c32 a = srcf[tid];
    c32 b = srcf[tid + 1024];
    c32 c = srcf[tid + 2048];
    c32 d = srcf[tid + 3072];
    c32 apc = cadd(a, c), amc = csub(a, c);
    c32 bpd = cadd(b, d), bmd = csub(b, d);
    int wb = tid + 3*jm;
    dstf[wb] = cadd(apc, bpd);
    dstf[wb + sstride]   = cmul(w1, make_float2(amc.x - bmd.y, amc.y + bmd.x));
    dstf[wb + 2*sstride] = cmul(w2, csub(apc, bpd));
    dstf[wb + 3*sstride] = cmul(w3, make_float2(amc.x + bmd.y, amc.y - bmd.x));
    __syncthreads();
    c32* t = srcf; srcf = dstf; dstf = t;
    sstride <<= 2;
  }

  // even stage count -> result in Zs (= srcf); z[m] = (x[2m], x[2m+1])
  {
    float4* o4 = (float4*)(out + (size_t)h*MF);
    const float4* s4 = (const float4*)srcf;
    o4[tid] = s4[tid];
    o4[tid + 1024] = s4[tid + 1024];
  }
}

extern "C" void kernel_launch(void* const* d_in, const int* in_sizes, int n_in,
                              void* d_out, int out_size, void* d_ws, size_t ws_size,
                              hipStream_t stream) {
  const float* log_dt = (const float*)d_in[0];
  const float* invwr  = (const float*)d_in[1];
  const float* wimag  = (const float*)d_in[2];
  const float* P      = (const float*)d_in[3];
  const float* B      = (const float*)d_in[4];
  const float* C      = (const float*)d_in[5];
  float* Sws = (float*)d_ws;                 // 512 blocks * 64 floats = 128 KB
  c32*   out = (c32*)d_out;                  // (H,8192) fp32 = (H,4096) c32
  (void)in_sizes; (void)n_in; (void)out_size; (void)ws_size;

  ssk_S<<<2*HH, 512, 0, stream>>>(log_dt, invwr, wimag, P, C, Sws);
  ssk_B<<<HH, 1024, 0, stream>>>(log_dt, invwr, wimag, P, B, C, Sws, out);
}